// Round 3
// baseline (2587.390 us; speedup 1.0000x reference)
//
#include <hip/hip_runtime.h>

typedef short s8v __attribute__((ext_vector_type(8)));
typedef float f4v __attribute__((ext_vector_type(4)));

__device__ __forceinline__ unsigned short f2bf(float x) {
  union { float f; unsigned u; } v; v.f = x;
  unsigned r = v.u + 0x7fffu + ((v.u >> 16) & 1u);
  return (unsigned short)(r >> 16);
}
__device__ __forceinline__ float bf2f(unsigned u16) {
  union { unsigned u; float f; } v; v.u = u16 << 16;
  return v.f;
}
__device__ __forceinline__ s8v as_s8(int4 v) { union { int4 i; s8v s; } u; u.i = v; return u.s; }
__device__ __forceinline__ f4v as_f4(int4 v) { union { int4 i; f4v f; } u; u.i = v; return u.f; }
__device__ __forceinline__ int4 as_i4(f4v v) { union { f4v f; int4 i; } u; u.f = v; return u.i; }

// ---------------- prep: bf16 casts + weight reorg + accum zero ----------------
__global__ __launch_bounds__(256) void prep_kernel(
    const float* __restrict__ q, const float* __restrict__ k,
    const float* __restrict__ w1, const float* __restrict__ w2, const float* __restrict__ w3,
    unsigned short* __restrict__ Qb, unsigned short* __restrict__ Kb,
    unsigned short* __restrict__ W1, unsigned short* __restrict__ W2,
    unsigned short* __restrict__ W3, float* __restrict__ accum) {
  int idx = blockIdx.x * 256 + threadIdx.x;
  const int NQ = 2048 * 512;
  if (idx < NQ) { Qb[idx] = f2bf(q[idx]); return; }
  idx -= NQ;
  if (idx < NQ) { Kb[idx] = f2bf(k[idx]); return; }
  idx -= NQ;
  if (idx < 3072) {                      // W1p [3 j][32 m][32 k]; k<16: dy=2j taps, k>=16: dy=2j+1
    int j = idx >> 10, m = (idx >> 5) & 31, kk = idx & 31;
    int half = kk >> 4, kl = kk & 15, dy = 2 * j + half;
    float v = 0.f;
    if (m < 30 && kl < 10 && dy < 5) v = w1[m * 50 + (kl & 1) * 25 + dy * 5 + (kl >> 1)];
    W1[idx] = f2bf(v); return;
  }
  idx -= 3072;
  if (idx < 25600) {                     // W2 [5 dy][32 m][160 kk], kk = dx*32 + c
    int dy = idx / 5120, r = idx - dy * 5120, m = r / 160, kk = r - m * 160;
    int c = kk & 31, dx = kk >> 5;
    float v = 0.f;
    if (m < 30 && c < 30) v = w2[m * 750 + c * 25 + dy * 5 + dx];
    W2[idx] = f2bf(v); return;
  }
  idx -= 25600;
  if (idx < 288) {                       // W3 [9 dd=dy*3+dx][32 c]
    int dd = idx >> 5, c = idx & 31;
    float v = (c < 30) ? w3[c * 9 + dd] : 0.f;
    W3[idx] = f2bf(v); return;
  }
  idx -= 288;
  if (idx == 0) *accum = 0.f;
}

// ---------------- row norms ----------------
__global__ __launch_bounds__(256) void norms_kernel(
    const float* __restrict__ q, const float* __restrict__ k,
    float* __restrict__ nq, float* __restrict__ nk) {
  int wv = threadIdx.x >> 6, l = threadIdx.x & 63;
  int row = blockIdx.x * 4 + wv;
  const float* src = (row < 2048) ? (q + row * 512) : (k + (row - 2048) * 512);
  float s = 0.f;
  for (int i = l; i < 512; i += 64) { float v = src[i]; s += v * v; }
  for (int off = 32; off; off >>= 1) s += __shfl_xor(s, off);
  if (l == 0) { if (row < 2048) nq[row] = s; else nk[row - 2048] = s; }
}

// ---------------- D = cdist GEMM (bf16 MFMA cross-term, fp32 norms) ----------------
__global__ __launch_bounds__(256) void dgemm_kernel(
    const unsigned short* __restrict__ Qb, const unsigned short* __restrict__ Kb,
    const float* __restrict__ nq, const float* __restrict__ nk,
    float* __restrict__ Dout) {
  __shared__ int4 sm[2 * 128 * 9];
  const int t = threadIdx.x;
  const int bm = blockIdx.x, bn = blockIdx.y;
  const int wv = t >> 6, l = t & 63;
  const int m0 = (wv & 1) * 64, n0 = (wv >> 1) * 64;
  const int l15 = l & 15, q4 = l >> 4;
  f4v acc[4][4] = {};
  const int4* Qg = (const int4*)Qb;
  const int4* Kg = (const int4*)Kb;
  for (int kt = 0; kt < 8; ++kt) {
    __syncthreads();
#pragma unroll
    for (int i = 0; i < 4; ++i) {
      int c = t + i * 256;
      int row = c >> 3, kq = c & 7;
      sm[row * 9 + kq]        = Qg[(bm * 128 + row) * 64 + kt * 8 + kq];
      sm[1152 + row * 9 + kq] = Kg[(bn * 128 + row) * 64 + kt * 8 + kq];
    }
    __syncthreads();
#pragma unroll
    for (int s = 0; s < 2; ++s) {
      s8v af[4], bfr[4];
#pragma unroll
      for (int mt = 0; mt < 4; ++mt)
        af[mt] = as_s8(sm[(m0 + mt * 16 + l15) * 9 + s * 4 + q4]);
#pragma unroll
      for (int nt = 0; nt < 4; ++nt)
        bfr[nt] = as_s8(sm[1152 + (n0 + nt * 16 + l15) * 9 + s * 4 + q4]);
#pragma unroll
      for (int mt = 0; mt < 4; ++mt)
#pragma unroll
        for (int nt = 0; nt < 4; ++nt)
          acc[mt][nt] = __builtin_amdgcn_mfma_f32_16x16x32_bf16(af[mt], bfr[nt], acc[mt][nt], 0, 0, 0);
    }
  }
  float nkv[4];
#pragma unroll
  for (int nt = 0; nt < 4; ++nt) nkv[nt] = nk[bn * 128 + n0 + nt * 16 + l15];
#pragma unroll
  for (int mt = 0; mt < 4; ++mt)
#pragma unroll
    for (int reg = 0; reg < 4; ++reg) {
      int gr = bm * 128 + m0 + mt * 16 + q4 * 4 + reg;
      float nqv = nq[gr];
#pragma unroll
      for (int nt = 0; nt < 4; ++nt) {
        int gc = bn * 128 + n0 + nt * 16 + l15;
        float d2 = nqv + nkv[nt] - 2.f * acc[mt][nt][reg];
        Dout[gr * 2048 + gc] = sqrtf(fmaxf(d2, 0.f));
      }
    }
}

// ---------------- fused conv1+conv2+conv3+residual, row-pipelined ----------------
// Tile 62 out px x 32 out rows. 12 waves: w0-7 conv2, w8-9 conv1, w10-11 conv3+staging.
// LDS: dps 8-row ring [8][96] u32; a1s [2][80 px][4 slot] int4 swizzled;
//      a2s [2][68 px][4 slot] int4 swizzled (single bf16).
__global__ __launch_bounds__(768, 3) void fused_conv(
    const float* __restrict__ Dmat, const float* __restrict__ lq, const float* __restrict__ lk,
    const unsigned short* __restrict__ W1g, const unsigned short* __restrict__ W2g,
    const unsigned short* __restrict__ W3g,
    const float* __restrict__ b1, const float* __restrict__ b2, const float* __restrict__ b3,
    float* __restrict__ Sout) {
  __shared__ int4 a1s[640];       // [2][80][4]
  __shared__ int4 a2s[544];       // [2][68][4]
  __shared__ unsigned dps[768];   // [8][96]
  const int t = threadIdx.x;
  const int wv = t >> 6, l = t & 63, l15 = l & 15, q4 = l >> 4;
  const int x0 = blockIdx.x * 62, y0 = blockIdx.y * 32;

  int4 uni[25];     // conv2: A2[dy][s] ; conv3: acc ring [tt][4]
  int4 uni2[5];     // conv2: acc ring[5] ; conv1: A1p[j] ; conv3: A3[dx]
  float bias4[4];
  const int cls = (wv < 8) ? 0 : (wv < 10 ? 1 : 2);
  const int mb = (cls == 0) ? (wv >> 2) : (wv & 1);
  const int T2 = wv & 3;
  const int T3 = (wv - 10) * 2;

  if (cls == 0) {
    const int4* W2i = (const int4*)W2g;
#pragma unroll
    for (int d = 0; d < 5; ++d)
#pragma unroll
      for (int s = 0; s < 5; ++s)
        uni[d * 5 + s] = W2i[(d * 32 + mb * 16 + l15) * 20 + s * 4 + q4];
#pragma unroll
    for (int j = 0; j < 5; ++j) uni2[j] = make_int4(0, 0, 0, 0);
#pragma unroll
    for (int i = 0; i < 4; ++i) {
      int ch = mb * 16 + q4 * 4 + i;
      bias4[i] = (ch < 30) ? b2[ch] : 0.f;
    }
  } else if (cls == 1) {
    const int4* W1i = (const int4*)W1g;
#pragma unroll
    for (int j = 0; j < 3; ++j) uni2[j] = W1i[(j * 32 + mb * 16 + l15) * 4 + q4];
#pragma unroll
    for (int i = 0; i < 4; ++i) {
      int ch = mb * 16 + q4 * 4 + i;
      bias4[i] = (ch < 30) ? b1[ch] : 0.f;
    }
  } else {
    const int4* W3i = (const int4*)W3g;
#pragma unroll
    for (int dx = 0; dx < 3; ++dx)
      uni2[dx] = (l15 < 3) ? W3i[(l15 * 3 + dx) * 4 + q4] : make_int4(0, 0, 0, 0);
#pragma unroll
    for (int j = 0; j < 8; ++j) uni[j] = make_int4(0, 0, 0, 0);
    bias4[0] = b3[0];
  }
  // prefill DP rows y0-5 .. y0-1
  if (t < 480) {
    int row = y0 - 5 + t / 96, px = t % 96;
    int gx = x0 - 5 + px;
    unsigned v = 0u;
    if (row >= 0 && gx >= 0 && gx < 2048) {
      float Dv = Dmat[row * 2048 + gx];
      float Pv = fabsf(lq[row] - lk[gx]);
      v = (unsigned)f2bf(Dv) | ((unsigned)f2bf(Pv) << 16);
    }
    dps[(row & 7) * 96 + px] = v;
  }
  // zero act2 pad px 64..67 (both slots)
  if (t >= 480 && t < 512) {
    int i = t - 480;
    int sl = i >> 4, rem = i & 15;
    a2s[(sl * 68 + 64 + (rem >> 2)) * 4 + (rem & 3)] = make_int4(0, 0, 0, 0);
  }
  __syncthreads();

  for (int r = y0 - 3; r <= y0 + 36; ++r) {
    if (cls == 0) {
      // ---- conv2: consume act1 row rc = r-1 (5-dy sliding accs) ----
      int rc = r - 1;
      if (rc >= y0 - 3 && rc <= y0 + 34) {
        int sl = rc & 1;
#pragma unroll
        for (int s = 0; s < 5; ++s) {
          int px = T2 * 16 + l15 + s;
          s8v B = as_s8(a1s[(sl * 80 + px) * 4 + (q4 ^ ((px >> 1) & 3))]);
#pragma unroll
          for (int d = 0; d < 5; ++d)
            uni2[4 - d] = as_i4(__builtin_amdgcn_mfma_f32_16x16x32_bf16(
                as_s8(uni[d * 5 + s]), B, as_f4(uni2[4 - d]), 0, 0, 0));
        }
      }
      // ---- emit act2 row r2c = r-3 (single bf16, swizzled) ----
      int r2c = r - 3;
      if (r2c >= y0 - 1 && r2c <= y0 + 32) {
        int px2 = T2 * 16 + l15;
        int gx2 = x0 - 1 + px2;
        bool ok = (r2c >= 0 && r2c < 2048 && gx2 >= 0 && gx2 < 2048);
        f4v a = as_f4(uni2[0]);
        ushort4 hv;
        hv.x = f2bf(ok ? fmaxf(a[0] + bias4[0], 0.f) : 0.f);
        hv.y = f2bf(ok ? fmaxf(a[1] + bias4[1], 0.f) : 0.f);
        hv.z = f2bf(ok ? fmaxf(a[2] + bias4[2], 0.f) : 0.f);
        hv.w = f2bf(ok ? fmaxf(a[3] + bias4[3], 0.f) : 0.f);
        int slot = (mb * 2 + (q4 >> 1)) ^ ((px2 >> 1) & 3);
        *(ushort4*)((unsigned short*)a2s + ((r2c & 1) * 68 + px2) * 32 + slot * 8 + (q4 & 1) * 4) = hv;
      }
#pragma unroll
      for (int j = 0; j < 4; ++j) uni2[j] = uni2[j + 1];
      uni2[4] = make_int4(0, 0, 0, 0);
    } else if (cls == 1) {
      // ---- conv1: produce act1 row r directly (dy-pair k-packed, 3 MFMA/px-tile) ----
      if (r >= y0 - 3 && r <= y0 + 34) {
        bool rowok = (r >= 0 && r < 2048);
#pragma unroll
        for (int T1 = 0; T1 < 5; ++T1) {
          int px = T1 * 16 + l15;
          f4v acc = {0.f, 0.f, 0.f, 0.f};
#pragma unroll
          for (int j = 0; j < 3; ++j) {
            int rlo = r - 2 + 2 * j;
            int rowsel = (j == 2) ? rlo : ((q4 < 2) ? rlo : (rlo + 1));
            int4 bi = *(const int4*)(dps + (rowsel & 7) * 96 + px + (q4 & 1) * 4);
            acc = __builtin_amdgcn_mfma_f32_16x16x32_bf16(as_s8(uni2[j]), as_s8(bi), acc, 0, 0, 0);
          }
          int gx = x0 - 3 + px;
          bool ok = rowok && gx >= 0 && gx < 2048;
          ushort4 sv;
          sv.x = f2bf(ok ? fmaxf(acc[0] + bias4[0], 0.f) : 0.f);
          sv.y = f2bf(ok ? fmaxf(acc[1] + bias4[1], 0.f) : 0.f);
          sv.z = f2bf(ok ? fmaxf(acc[2] + bias4[2], 0.f) : 0.f);
          sv.w = f2bf(ok ? fmaxf(acc[3] + bias4[3], 0.f) : 0.f);
          int slot = (mb * 2 + (q4 >> 1)) ^ ((px >> 1) & 3);
          *(ushort4*)((unsigned short*)a1s + ((r & 1) * 80 + px) * 32 + slot * 8 + (q4 & 1) * 4) = sv;
        }
      }
    } else {
      // ---- staging loads for DP row rs = r+3 (stored at end of iter) ----
      int rs = r + 3;
      bool stact = (rs <= y0 + 36);
      int spx = (wv == 10) ? l : (64 + l);
      bool lact = stact && (spx < 96);
      int sgx = x0 - 5 + spx;
      unsigned pv = 0u;
      if (lact && rs < 2048 && sgx >= 0 && sgx < 2048) {
        float Dv = Dmat[rs * 2048 + sgx];
        float Pv = fabsf(lq[rs] - lk[sgx]);
        pv = (unsigned)f2bf(Dv) | ((unsigned)f2bf(Pv) << 16);
      }
      // ---- conv3: consume act2 row a = r-4 (m=dy trick: 3 MFMA per 16px tile) ----
      int a = r - 4;
      if (a >= y0 - 1 && a <= y0 + 32) {
        int sl = a & 1;
#pragma unroll
        for (int tt = 0; tt < 2; ++tt) {
          f4v acc3 = {0.f, 0.f, 0.f, 0.f};
#pragma unroll
          for (int dx = 0; dx < 3; ++dx) {
            int px2 = (T3 + tt) * 16 + l15 + dx;
            s8v B = as_s8(a2s[(sl * 68 + px2) * 4 + (q4 ^ ((px2 >> 1) & 3))]);
            acc3 = __builtin_amdgcn_mfma_f32_16x16x32_bf16(as_s8(uni2[dx]), B, acc3, 0, 0, 0);
          }
          uni[tt * 4 + (a & 3)] = as_i4(acc3);
        }
      }
      // ---- emit out row y = r-5 : conv3 + bias + D residual ----
      int y = r - 5;
      if (y >= y0 && y <= y0 + 31) {
#pragma unroll
        for (int tt = 0; tt < 2; ++tt) {
          int ox = (T3 + tt) * 16 + l15;
          int gx = x0 + ox;
          if (q4 == 0 && ox < 62 && gx < 2048) {
            float val = as_f4(uni[tt * 4 + ((y - 1) & 3)])[0]
                      + as_f4(uni[tt * 4 + (y & 3)])[1]
                      + as_f4(uni[tt * 4 + ((y + 1) & 3)])[2]
                      + bias4[0] + Dmat[y * 2048 + gx];
            Sout[y * 2048 + gx] = val;
          }
        }
      }
      if (lact) dps[(rs & 7) * 96 + spx] = pv;
    }
    __syncthreads();
  }
}

// ---------------- row softmax (in-place on d_out) + dis accumulation ----------------
__global__ __launch_bounds__(256) void softmax_kernel(
    float* __restrict__ S, const float* __restrict__ Dmat, float* __restrict__ accum) {
  const int row = blockIdx.x, t = threadIdx.x;
  float* Srow = S + row * 2048;
  const float* Drow = Dmat + row * 2048;
  float sv[8], dv[8];
  float mx = -1e30f;
#pragma unroll
  for (int i = 0; i < 8; ++i) {
    sv[i] = -Srow[t + i * 256];
    dv[i] = Drow[t + i * 256];
    mx = fmaxf(mx, sv[i]);
  }
  __shared__ float red[4], redz[4], redw[4];
  for (int off = 32; off; off >>= 1) mx = fmaxf(mx, __shfl_xor(mx, off));
  const int wv = t >> 6, l = t & 63;
  if (l == 0) red[wv] = mx;
  __syncthreads();
  mx = fmaxf(fmaxf(red[0], red[1]), fmaxf(red[2], red[3]));
  float z = 0.f, w = 0.f, ev[8];
#pragma unroll
  for (int i = 0; i < 8; ++i) {
    ev[i] = __expf(sv[i] - mx);
    z += ev[i];
    w += ev[i] * dv[i];
  }
  for (int off = 32; off; off >>= 1) { z += __shfl_xor(z, off); w += __shfl_xor(w, off); }
  if (l == 0) { redz[wv] = z; redw[wv] = w; }
  __syncthreads();
  z = redz[0] + redz[1] + redz[2] + redz[3];
  w = redw[0] + redw[1] + redw[2] + redw[3];
  float inv = 1.f / z;
#pragma unroll
  for (int i = 0; i < 8; ++i) Srow[t + i * 256] = ev[i] * inv;
  if (t == 0) atomicAdd(accum, w * inv);
}

__global__ void finalize_kernel(const float* __restrict__ accum, float* __restrict__ out) {
  if (threadIdx.x == 0) out[0] = accum[0] * (1.f / 2048.f);
}

// ---------------- host ----------------
extern "C" void kernel_launch(void* const* d_in, const int* in_sizes, int n_in,
                              void* d_out, int out_size, void* d_ws, size_t ws_size,
                              hipStream_t stream) {
  const float* seq_q = (const float*)d_in[0];
  const float* seq_k = (const float*)d_in[1];
  const float* len_q = (const float*)d_in[2];
  const float* len_k = (const float*)d_in[3];
  const float* w1 = (const float*)d_in[4];
  const float* b1 = (const float*)d_in[5];
  const float* w2 = (const float*)d_in[6];
  const float* b2 = (const float*)d_in[7];
  const float* w3 = (const float*)d_in[8];
  const float* b3 = (const float*)d_in[9];

  char* ws = (char*)d_ws;
  unsigned short* Qb  = (unsigned short*)(ws);                         // 2 MiB
  unsigned short* Kb  = (unsigned short*)(ws + ((size_t)2 << 20));     // 2 MiB
  float* nq           = (float*)(ws + ((size_t)4 << 20));              // 8 KiB
  float* nk           = (float*)(ws + ((size_t)4 << 20) + 16384);
  unsigned short* W1  = (unsigned short*)(ws + ((size_t)4 << 20) + 32768);   // 6 KiB (packed)
  unsigned short* W2  = (unsigned short*)(ws + ((size_t)4 << 20) + 65536);   // 50 KiB
  unsigned short* W3  = (unsigned short*)(ws + ((size_t)4 << 20) + 131072);  // 576 B
  float* accum        = (float*)(ws + ((size_t)4 << 20) + 163840);
  float* Dmat         = (float*)(ws + ((size_t)5 << 20));              // 16 MiB
  float* out = (float*)d_out;

  const int prep_total = 2 * 2048 * 512 + 3072 + 25600 + 288 + 1;
  prep_kernel<<<(prep_total + 255) / 256, 256, 0, stream>>>(
      seq_q, seq_k, w1, w2, w3, Qb, Kb, W1, W2, W3, accum);
  norms_kernel<<<1024, 256, 0, stream>>>(seq_q, seq_k, nq, nk);
  dgemm_kernel<<<dim3(16, 16), 256, 0, stream>>>(Qb, Kb, nq, nk, Dmat);
  fused_conv<<<dim3(34, 64), 768, 0, stream>>>(
      Dmat, len_q, len_k, W1, W2, W3, b1, b2, b3, out);
  softmax_kernel<<<2048, 256, 0, stream>>>(out, Dmat, accum);
  finalize_kernel<<<1, 64, 0, stream>>>(accum, out + 4194304);
}

// Round 4
// 602.903 us; speedup vs baseline: 4.2916x; 4.2916x over previous
//
#include <hip/hip_runtime.h>

typedef short s8v __attribute__((ext_vector_type(8)));
typedef float f4v __attribute__((ext_vector_type(4)));

__device__ __forceinline__ unsigned short f2bf(float x) {
  union { float f; unsigned u; } v; v.f = x;
  unsigned r = v.u + 0x7fffu + ((v.u >> 16) & 1u);
  return (unsigned short)(r >> 16);
}
__device__ __forceinline__ float bf2f(unsigned u16) {
  union { unsigned u; float f; } v; v.u = u16 << 16;
  return v.f;
}
__device__ __forceinline__ s8v as_s8(int4 v) { union { int4 i; s8v s; } u; u.i = v; return u.s; }
__device__ __forceinline__ f4v as_f4(int4 v) { union { int4 i; f4v f; } u; u.i = v; return u.f; }
__device__ __forceinline__ int4 as_i4(f4v v) { union { f4v f; int4 i; } u; u.f = v; return u.i; }

// ---------------- prep: bf16 casts + weight reorg + accum zero ----------------
__global__ __launch_bounds__(256) void prep_kernel(
    const float* __restrict__ q, const float* __restrict__ k,
    const float* __restrict__ w1, const float* __restrict__ w2, const float* __restrict__ w3,
    unsigned short* __restrict__ Qb, unsigned short* __restrict__ Kb,
    unsigned short* __restrict__ W1, unsigned short* __restrict__ W2,
    unsigned short* __restrict__ W3, float* __restrict__ accum) {
  int idx = blockIdx.x * 256 + threadIdx.x;
  const int NQ = 2048 * 512;
  if (idx < NQ) { Qb[idx] = f2bf(q[idx]); return; }
  idx -= NQ;
  if (idx < NQ) { Kb[idx] = f2bf(k[idx]); return; }
  idx -= NQ;
  if (idx < 3072) {                      // W1p [3 j][32 m][32 k]; k<16: dy=2j taps, k>=16: dy=2j+1
    int j = idx >> 10, m = (idx >> 5) & 31, kk = idx & 31;
    int half = kk >> 4, kl = kk & 15, dy = 2 * j + half;
    float v = 0.f;
    if (m < 30 && kl < 10 && dy < 5) v = w1[m * 50 + (kl & 1) * 25 + dy * 5 + (kl >> 1)];
    W1[idx] = f2bf(v); return;
  }
  idx -= 3072;
  if (idx < 25600) {                     // W2 [5 dy][32 m][160 kk], kk = dx*32 + c
    int dy = idx / 5120, r = idx - dy * 5120, m = r / 160, kk = r - m * 160;
    int c = kk & 31, dx = kk >> 5;
    float v = 0.f;
    if (m < 30 && c < 30) v = w2[m * 750 + c * 25 + dy * 5 + dx];
    W2[idx] = f2bf(v); return;
  }
  idx -= 25600;
  if (idx < 288) {                       // W3 [9 dd=dy*3+dx][32 c]
    int dd = idx >> 5, c = idx & 31;
    float v = (c < 30) ? w3[c * 9 + dd] : 0.f;
    W3[idx] = f2bf(v); return;
  }
  idx -= 288;
  if (idx == 0) *accum = 0.f;
}

// ---------------- row norms ----------------
__global__ __launch_bounds__(256) void norms_kernel(
    const float* __restrict__ q, const float* __restrict__ k,
    float* __restrict__ nq, float* __restrict__ nk) {
  int wv = threadIdx.x >> 6, l = threadIdx.x & 63;
  int row = blockIdx.x * 4 + wv;
  const float* src = (row < 2048) ? (q + row * 512) : (k + (row - 2048) * 512);
  float s = 0.f;
  for (int i = l; i < 512; i += 64) { float v = src[i]; s += v * v; }
  for (int off = 32; off; off >>= 1) s += __shfl_xor(s, off);
  if (l == 0) { if (row < 2048) nq[row] = s; else nk[row - 2048] = s; }
}

// ---------------- D = cdist GEMM (bf16 MFMA cross-term, fp32 norms) ----------------
__global__ __launch_bounds__(256) void dgemm_kernel(
    const unsigned short* __restrict__ Qb, const unsigned short* __restrict__ Kb,
    const float* __restrict__ nq, const float* __restrict__ nk,
    float* __restrict__ Dout) {
  __shared__ int4 sm[2 * 128 * 9];
  const int t = threadIdx.x;
  const int bm = blockIdx.x, bn = blockIdx.y;
  const int wv = t >> 6, l = t & 63;
  const int m0 = (wv & 1) * 64, n0 = (wv >> 1) * 64;
  const int l15 = l & 15, q4 = l >> 4;
  f4v acc[4][4] = {};
  const int4* Qg = (const int4*)Qb;
  const int4* Kg = (const int4*)Kb;
  for (int kt = 0; kt < 8; ++kt) {
    __syncthreads();
#pragma unroll
    for (int i = 0; i < 4; ++i) {
      int c = t + i * 256;
      int row = c >> 3, kq = c & 7;
      sm[row * 9 + kq]        = Qg[(bm * 128 + row) * 64 + kt * 8 + kq];
      sm[1152 + row * 9 + kq] = Kg[(bn * 128 + row) * 64 + kt * 8 + kq];
    }
    __syncthreads();
#pragma unroll
    for (int s = 0; s < 2; ++s) {
      s8v af[4], bfr[4];
#pragma unroll
      for (int mt = 0; mt < 4; ++mt)
        af[mt] = as_s8(sm[(m0 + mt * 16 + l15) * 9 + s * 4 + q4]);
#pragma unroll
      for (int nt = 0; nt < 4; ++nt)
        bfr[nt] = as_s8(sm[1152 + (n0 + nt * 16 + l15) * 9 + s * 4 + q4]);
#pragma unroll
      for (int mt = 0; mt < 4; ++mt)
#pragma unroll
        for (int nt = 0; nt < 4; ++nt)
          acc[mt][nt] = __builtin_amdgcn_mfma_f32_16x16x32_bf16(af[mt], bfr[nt], acc[mt][nt], 0, 0, 0);
    }
  }
  float nkv[4];
#pragma unroll
  for (int nt = 0; nt < 4; ++nt) nkv[nt] = nk[bn * 128 + n0 + nt * 16 + l15];
#pragma unroll
  for (int mt = 0; mt < 4; ++mt)
#pragma unroll
    for (int reg = 0; reg < 4; ++reg) {
      int gr = bm * 128 + m0 + mt * 16 + q4 * 4 + reg;
      float nqv = nq[gr];
#pragma unroll
      for (int nt = 0; nt < 4; ++nt) {
        int gc = bn * 128 + n0 + nt * 16 + l15;
        float d2 = nqv + nkv[nt] - 2.f * acc[mt][nt][reg];
        Dout[gr * 2048 + gc] = sqrtf(fmaxf(d2, 0.f));
      }
    }
}

// ---------------- fused conv1+conv2+conv3+residual, row-pipelined ----------------
// Tile 62 out px x 32 out rows. 12 waves: w0-7 conv2, w8-9 conv1, w10-11 conv3+staging.
// LDS: dps 8-row ring [8][96] u32; a1s [2][80 px][4 slot] int4 swizzled;
//      a2s [2][68 px][4 slot] int4 swizzled (single bf16).
// NOTE: all register arrays indexed with compile-time constants ONLY (round-3
// regression: one dynamic index demoted the whole union array to scratch ->
// 7.9 GB of spill traffic).
__global__ __launch_bounds__(768, 3) void fused_conv(
    const float* __restrict__ Dmat, const float* __restrict__ lq, const float* __restrict__ lk,
    const unsigned short* __restrict__ W1g, const unsigned short* __restrict__ W2g,
    const unsigned short* __restrict__ W3g,
    const float* __restrict__ b1, const float* __restrict__ b2, const float* __restrict__ b3,
    float* __restrict__ Sout) {
  __shared__ int4 a1s[640];       // [2][80][4]
  __shared__ int4 a2s[544];       // [2][68][4]
  __shared__ unsigned dps[768];   // [8][96]
  const int t = threadIdx.x;
  const int wv = t >> 6, l = t & 63, l15 = l & 15, q4 = l >> 4;
  const int x0 = blockIdx.x * 62, y0 = blockIdx.y * 32;

  int4 uni[25];     // conv2: A2[dy][s] ; conv3: shift regs [tt][3] = prev2,prev,cur
  int4 uni2[5];     // conv2: acc ring[5] ; conv1: A1p[j] ; conv3: A3[dx]
  float bias4[4];
  const int cls = (wv < 8) ? 0 : (wv < 10 ? 1 : 2);
  const int mb = (cls == 0) ? (wv >> 2) : (wv & 1);
  const int T2 = wv & 3;
  const int T3 = (wv - 10) * 2;

  if (cls == 0) {
    const int4* W2i = (const int4*)W2g;
#pragma unroll
    for (int d = 0; d < 5; ++d)
#pragma unroll
      for (int s = 0; s < 5; ++s)
        uni[d * 5 + s] = W2i[(d * 32 + mb * 16 + l15) * 20 + s * 4 + q4];
#pragma unroll
    for (int j = 0; j < 5; ++j) uni2[j] = make_int4(0, 0, 0, 0);
#pragma unroll
    for (int i = 0; i < 4; ++i) {
      int ch = mb * 16 + q4 * 4 + i;
      bias4[i] = (ch < 30) ? b2[ch] : 0.f;
    }
  } else if (cls == 1) {
    const int4* W1i = (const int4*)W1g;
#pragma unroll
    for (int j = 0; j < 3; ++j) uni2[j] = W1i[(j * 32 + mb * 16 + l15) * 4 + q4];
#pragma unroll
    for (int i = 0; i < 4; ++i) {
      int ch = mb * 16 + q4 * 4 + i;
      bias4[i] = (ch < 30) ? b1[ch] : 0.f;
    }
  } else {
    const int4* W3i = (const int4*)W3g;
#pragma unroll
    for (int dx = 0; dx < 3; ++dx)
      uni2[dx] = (l15 < 3) ? W3i[(l15 * 3 + dx) * 4 + q4] : make_int4(0, 0, 0, 0);
#pragma unroll
    for (int j = 0; j < 6; ++j) uni[j] = make_int4(0, 0, 0, 0);
    bias4[0] = b3[0];
  }
  // prefill DP rows y0-5 .. y0-1
  if (t < 480) {
    int row = y0 - 5 + t / 96, px = t % 96;
    int gx = x0 - 5 + px;
    unsigned v = 0u;
    if (row >= 0 && gx >= 0 && gx < 2048) {
      float Dv = Dmat[row * 2048 + gx];
      float Pv = fabsf(lq[row] - lk[gx]);
      v = (unsigned)f2bf(Dv) | ((unsigned)f2bf(Pv) << 16);
    }
    dps[(row & 7) * 96 + px] = v;
  }
  // zero act2 pad px 64..67 (both slots)
  if (t >= 480 && t < 512) {
    int i = t - 480;
    int sl = i >> 4, rem = i & 15;
    a2s[(sl * 68 + 64 + (rem >> 2)) * 4 + (rem & 3)] = make_int4(0, 0, 0, 0);
  }
  __syncthreads();

  for (int r = y0 - 3; r <= y0 + 36; ++r) {
    if (cls == 0) {
      // ---- conv2: consume act1 row rc = r-1 (5-dy sliding accs) ----
      int rc = r - 1;
      if (rc >= y0 - 3 && rc <= y0 + 34) {
        int sl = rc & 1;
#pragma unroll
        for (int s = 0; s < 5; ++s) {
          int px = T2 * 16 + l15 + s;
          s8v B = as_s8(a1s[(sl * 80 + px) * 4 + (q4 ^ ((px >> 1) & 3))]);
#pragma unroll
          for (int d = 0; d < 5; ++d)
            uni2[4 - d] = as_i4(__builtin_amdgcn_mfma_f32_16x16x32_bf16(
                as_s8(uni[d * 5 + s]), B, as_f4(uni2[4 - d]), 0, 0, 0));
        }
      }
      // ---- emit act2 row r2c = r-3 (single bf16, swizzled) ----
      int r2c = r - 3;
      if (r2c >= y0 - 1 && r2c <= y0 + 32) {
        int px2 = T2 * 16 + l15;
        int gx2 = x0 - 1 + px2;
        bool ok = (r2c >= 0 && r2c < 2048 && gx2 >= 0 && gx2 < 2048);
        f4v a = as_f4(uni2[0]);
        ushort4 hv;
        hv.x = f2bf(ok ? fmaxf(a[0] + bias4[0], 0.f) : 0.f);
        hv.y = f2bf(ok ? fmaxf(a[1] + bias4[1], 0.f) : 0.f);
        hv.z = f2bf(ok ? fmaxf(a[2] + bias4[2], 0.f) : 0.f);
        hv.w = f2bf(ok ? fmaxf(a[3] + bias4[3], 0.f) : 0.f);
        int slot = (mb * 2 + (q4 >> 1)) ^ ((px2 >> 1) & 3);
        *(ushort4*)((unsigned short*)a2s + ((r2c & 1) * 68 + px2) * 32 + slot * 8 + (q4 & 1) * 4) = hv;
      }
#pragma unroll
      for (int j = 0; j < 4; ++j) uni2[j] = uni2[j + 1];
      uni2[4] = make_int4(0, 0, 0, 0);
    } else if (cls == 1) {
      // ---- conv1: produce act1 row r directly (dy-pair k-packed, 3 MFMA/px-tile) ----
      if (r >= y0 - 3 && r <= y0 + 34) {
        bool rowok = (r >= 0 && r < 2048);
#pragma unroll
        for (int T1 = 0; T1 < 5; ++T1) {
          int px = T1 * 16 + l15;
          f4v acc = {0.f, 0.f, 0.f, 0.f};
#pragma unroll
          for (int j = 0; j < 3; ++j) {
            int rlo = r - 2 + 2 * j;
            int rowsel = (j == 2) ? rlo : ((q4 < 2) ? rlo : (rlo + 1));
            int4 bi = *(const int4*)(dps + (rowsel & 7) * 96 + px + (q4 & 1) * 4);
            acc = __builtin_amdgcn_mfma_f32_16x16x32_bf16(as_s8(uni2[j]), as_s8(bi), acc, 0, 0, 0);
          }
          int gx = x0 - 3 + px;
          bool ok = rowok && gx >= 0 && gx < 2048;
          ushort4 sv;
          sv.x = f2bf(ok ? fmaxf(acc[0] + bias4[0], 0.f) : 0.f);
          sv.y = f2bf(ok ? fmaxf(acc[1] + bias4[1], 0.f) : 0.f);
          sv.z = f2bf(ok ? fmaxf(acc[2] + bias4[2], 0.f) : 0.f);
          sv.w = f2bf(ok ? fmaxf(acc[3] + bias4[3], 0.f) : 0.f);
          int slot = (mb * 2 + (q4 >> 1)) ^ ((px >> 1) & 3);
          *(ushort4*)((unsigned short*)a1s + ((r & 1) * 80 + px) * 32 + slot * 8 + (q4 & 1) * 4) = sv;
        }
      }
    } else {
      // ---- staging loads for DP row rs = r+3 (stored at end of iter) ----
      int rs = r + 3;
      bool stact = (rs <= y0 + 36);
      int spx = (wv == 10) ? l : (64 + l);
      bool lact = stact && (spx < 96);
      int sgx = x0 - 5 + spx;
      unsigned pv = 0u;
      if (lact && rs < 2048 && sgx >= 0 && sgx < 2048) {
        float Dv = Dmat[rs * 2048 + sgx];
        float Pv = fabsf(lq[rs] - lk[sgx]);
        pv = (unsigned)f2bf(Dv) | ((unsigned)f2bf(Pv) << 16);
      }
      // ---- conv3: consume act2 row a = r-4 (m=dy trick: 3 MFMA per 16px tile) ----
      // shift registers: uni[tt*3+0]=prev2 (row a-2), uni[tt*3+1]=prev (a-1), uni[tt*3+2]=cur (a)
      int a = r - 4;
      if (a >= y0 - 1 && a <= y0 + 32) {
        int sl = a & 1;
#pragma unroll
        for (int tt = 0; tt < 2; ++tt) {
          f4v acc3 = {0.f, 0.f, 0.f, 0.f};
#pragma unroll
          for (int dx = 0; dx < 3; ++dx) {
            int px2 = (T3 + tt) * 16 + l15 + dx;
            s8v B = as_s8(a2s[(sl * 68 + px2) * 4 + (q4 ^ ((px2 >> 1) & 3))]);
            acc3 = __builtin_amdgcn_mfma_f32_16x16x32_bf16(as_s8(uni2[dx]), B, acc3, 0, 0, 0);
          }
          uni[tt * 3 + 2] = as_i4(acc3);
        }
      }
      // ---- emit out row y = r-5 : out[y] = acc(y-1)[0] + acc(y)[1] + acc(y+1)[2] ----
      int y = r - 5;
      if (y >= y0 && y <= y0 + 31) {
#pragma unroll
        for (int tt = 0; tt < 2; ++tt) {
          int ox = (T3 + tt) * 16 + l15;
          int gx = x0 + ox;
          if (q4 == 0 && ox < 62 && gx < 2048) {
            float val = as_f4(uni[tt * 3 + 0])[0]
                      + as_f4(uni[tt * 3 + 1])[1]
                      + as_f4(uni[tt * 3 + 2])[2]
                      + bias4[0] + Dmat[y * 2048 + gx];
            Sout[y * 2048 + gx] = val;
          }
        }
      }
      // shift (static moves)
#pragma unroll
      for (int tt = 0; tt < 2; ++tt) {
        uni[tt * 3 + 0] = uni[tt * 3 + 1];
        uni[tt * 3 + 1] = uni[tt * 3 + 2];
      }
      if (lact) dps[(rs & 7) * 96 + spx] = pv;
    }
    __syncthreads();
  }
}

// ---------------- row softmax (in-place on d_out) + dis accumulation ----------------
__global__ __launch_bounds__(256) void softmax_kernel(
    float* __restrict__ S, const float* __restrict__ Dmat, float* __restrict__ accum) {
  const int row = blockIdx.x, t = threadIdx.x;
  float* Srow = S + row * 2048;
  const float* Drow = Dmat + row * 2048;
  float sv[8], dv[8];
  float mx = -1e30f;
#pragma unroll
  for (int i = 0; i < 8; ++i) {
    sv[i] = -Srow[t + i * 256];
    dv[i] = Drow[t + i * 256];
    mx = fmaxf(mx, sv[i]);
  }
  __shared__ float red[4], redz[4], redw[4];
  for (int off = 32; off; off >>= 1) mx = fmaxf(mx, __shfl_xor(mx, off));
  const int wv = t >> 6, l = t & 63;
  if (l == 0) red[wv] = mx;
  __syncthreads();
  mx = fmaxf(fmaxf(red[0], red[1]), fmaxf(red[2], red[3]));
  float z = 0.f, w = 0.f, ev[8];
#pragma unroll
  for (int i = 0; i < 8; ++i) {
    ev[i] = __expf(sv[i] - mx);
    z += ev[i];
    w += ev[i] * dv[i];
  }
  for (int off = 32; off; off >>= 1) { z += __shfl_xor(z, off); w += __shfl_xor(w, off); }
  if (l == 0) { redz[wv] = z; redw[wv] = w; }
  __syncthreads();
  z = redz[0] + redz[1] + redz[2] + redz[3];
  w = redw[0] + redw[1] + redw[2] + redw[3];
  float inv = 1.f / z;
#pragma unroll
  for (int i = 0; i < 8; ++i) Srow[t + i * 256] = ev[i] * inv;
  if (t == 0) atomicAdd(accum, w * inv);
}

__global__ void finalize_kernel(const float* __restrict__ accum, float* __restrict__ out) {
  if (threadIdx.x == 0) out[0] = accum[0] * (1.f / 2048.f);
}

// ---------------- host ----------------
extern "C" void kernel_launch(void* const* d_in, const int* in_sizes, int n_in,
                              void* d_out, int out_size, void* d_ws, size_t ws_size,
                              hipStream_t stream) {
  const float* seq_q = (const float*)d_in[0];
  const float* seq_k = (const float*)d_in[1];
  const float* len_q = (const float*)d_in[2];
  const float* len_k = (const float*)d_in[3];
  const float* w1 = (const float*)d_in[4];
  const float* b1 = (const float*)d_in[5];
  const float* w2 = (const float*)d_in[6];
  const float* b2 = (const float*)d_in[7];
  const float* w3 = (const float*)d_in[8];
  const float* b3 = (const float*)d_in[9];

  char* ws = (char*)d_ws;
  unsigned short* Qb  = (unsigned short*)(ws);                         // 2 MiB
  unsigned short* Kb  = (unsigned short*)(ws + ((size_t)2 << 20));     // 2 MiB
  float* nq           = (float*)(ws + ((size_t)4 << 20));              // 8 KiB
  float* nk           = (float*)(ws + ((size_t)4 << 20) + 16384);
  unsigned short* W1  = (unsigned short*)(ws + ((size_t)4 << 20) + 32768);   // 6 KiB (packed)
  unsigned short* W2  = (unsigned short*)(ws + ((size_t)4 << 20) + 65536);   // 50 KiB
  unsigned short* W3  = (unsigned short*)(ws + ((size_t)4 << 20) + 131072);  // 576 B
  float* accum        = (float*)(ws + ((size_t)4 << 20) + 163840);
  float* Dmat         = (float*)(ws + ((size_t)5 << 20));              // 16 MiB
  float* out = (float*)d_out;

  const int prep_total = 2 * 2048 * 512 + 3072 + 25600 + 288 + 1;
  prep_kernel<<<(prep_total + 255) / 256, 256, 0, stream>>>(
      seq_q, seq_k, w1, w2, w3, Qb, Kb, W1, W2, W3, accum);
  norms_kernel<<<1024, 256, 0, stream>>>(seq_q, seq_k, nq, nk);
  dgemm_kernel<<<dim3(16, 16), 256, 0, stream>>>(Qb, Kb, nq, nk, Dmat);
  fused_conv<<<dim3(34, 64), 768, 0, stream>>>(
      Dmat, len_q, len_k, W1, W2, W3, b1, b2, b3, out);
  softmax_kernel<<<2048, 256, 0, stream>>>(out, Dmat, accum);
  finalize_kernel<<<1, 64, 0, stream>>>(accum, out + 4194304);
}

// Round 5
// 581.090 us; speedup vs baseline: 4.4527x; 1.0375x over previous
//
#include <hip/hip_runtime.h>

typedef short s8v __attribute__((ext_vector_type(8)));
typedef float f4v __attribute__((ext_vector_type(4)));

__device__ __forceinline__ unsigned short f2bf(float x) {
  union { float f; unsigned u; } v; v.f = x;
  unsigned r = v.u + 0x7fffu + ((v.u >> 16) & 1u);
  return (unsigned short)(r >> 16);
}
__device__ __forceinline__ float bf2f(unsigned u16) {
  union { unsigned u; float f; } v; v.u = u16 << 16;
  return v.f;
}
__device__ __forceinline__ s8v as_s8(int4 v) { union { int4 i; s8v s; } u; u.i = v; return u.s; }
__device__ __forceinline__ f4v as_f4(int4 v) { union { int4 i; f4v f; } u; u.i = v; return u.f; }
__device__ __forceinline__ int4 as_i4(f4v v) { union { f4v f; int4 i; } u; u.f = v; return u.i; }

// ---------------- prep: bf16 casts + weight reorg + accum zero ----------------
__global__ __launch_bounds__(256) void prep_kernel(
    const float* __restrict__ q, const float* __restrict__ k,
    const float* __restrict__ w1, const float* __restrict__ w2, const float* __restrict__ w3,
    unsigned short* __restrict__ Qb, unsigned short* __restrict__ Kb,
    unsigned short* __restrict__ W1, unsigned short* __restrict__ W2,
    unsigned short* __restrict__ W3, float* __restrict__ accum) {
  int idx = blockIdx.x * 256 + threadIdx.x;
  const int NQ = 2048 * 512;
  if (idx < NQ) { Qb[idx] = f2bf(q[idx]); return; }
  idx -= NQ;
  if (idx < NQ) { Kb[idx] = f2bf(k[idx]); return; }
  idx -= NQ;
  if (idx < 3072) {                      // W1p [3 j][32 m][32 k]; k<16: dy=2j taps, k>=16: dy=2j+1
    int j = idx >> 10, m = (idx >> 5) & 31, kk = idx & 31;
    int half = kk >> 4, kl = kk & 15, dy = 2 * j + half;
    float v = 0.f;
    if (m < 30 && kl < 10 && dy < 5) v = w1[m * 50 + (kl & 1) * 25 + dy * 5 + (kl >> 1)];
    W1[idx] = f2bf(v); return;
  }
  idx -= 3072;
  if (idx < 25600) {                     // W2 [5 dy][32 m][160 kk], kk = dx*32 + c
    int dy = idx / 5120, r = idx - dy * 5120, m = r / 160, kk = r - m * 160;
    int c = kk & 31, dx = kk >> 5;
    float v = 0.f;
    if (m < 30 && c < 30) v = w2[m * 750 + c * 25 + dy * 5 + dx];
    W2[idx] = f2bf(v); return;
  }
  idx -= 25600;
  if (idx < 288) {                       // W3 [9 dd=dy*3+dx][32 c]
    int dd = idx >> 5, c = idx & 31;
    float v = (c < 30) ? w3[c * 9 + dd] : 0.f;
    W3[idx] = f2bf(v); return;
  }
  idx -= 288;
  if (idx == 0) *accum = 0.f;
}

// ---------------- row norms ----------------
__global__ __launch_bounds__(256) void norms_kernel(
    const float* __restrict__ q, const float* __restrict__ k,
    float* __restrict__ nq, float* __restrict__ nk) {
  int wv = threadIdx.x >> 6, l = threadIdx.x & 63;
  int row = blockIdx.x * 4 + wv;
  const float* src = (row < 2048) ? (q + row * 512) : (k + (row - 2048) * 512);
  float s = 0.f;
  for (int i = l; i < 512; i += 64) { float v = src[i]; s += v * v; }
  for (int off = 32; off; off >>= 1) s += __shfl_xor(s, off);
  if (l == 0) { if (row < 2048) nq[row] = s; else nk[row - 2048] = s; }
}

// ---------------- D = cdist GEMM (bf16 MFMA cross-term, fp32 norms) ----------------
__global__ __launch_bounds__(256) void dgemm_kernel(
    const unsigned short* __restrict__ Qb, const unsigned short* __restrict__ Kb,
    const float* __restrict__ nq, const float* __restrict__ nk,
    const float* __restrict__ lq, const float* __restrict__ lk,
    float* __restrict__ Dout, unsigned* __restrict__ DPo) {
  __shared__ int4 sm[2 * 128 * 9];
  const int t = threadIdx.x;
  const int bm = blockIdx.x, bn = blockIdx.y;
  const int wv = t >> 6, l = t & 63;
  const int m0 = (wv & 1) * 64, n0 = (wv >> 1) * 64;
  const int l15 = l & 15, q4 = l >> 4;
  f4v acc[4][4] = {};
  const int4* Qg = (const int4*)Qb;
  const int4* Kg = (const int4*)Kb;
  for (int kt = 0; kt < 8; ++kt) {
    __syncthreads();
#pragma unroll
    for (int i = 0; i < 4; ++i) {
      int c = t + i * 256;
      int row = c >> 3, kq = c & 7;
      sm[row * 9 + kq]        = Qg[(bm * 128 + row) * 64 + kt * 8 + kq];
      sm[1152 + row * 9 + kq] = Kg[(bn * 128 + row) * 64 + kt * 8 + kq];
    }
    __syncthreads();
#pragma unroll
    for (int s = 0; s < 2; ++s) {
      s8v af[4], bfr[4];
#pragma unroll
      for (int mt = 0; mt < 4; ++mt)
        af[mt] = as_s8(sm[(m0 + mt * 16 + l15) * 9 + s * 4 + q4]);
#pragma unroll
      for (int nt = 0; nt < 4; ++nt)
        bfr[nt] = as_s8(sm[1152 + (n0 + nt * 16 + l15) * 9 + s * 4 + q4]);
#pragma unroll
      for (int mt = 0; mt < 4; ++mt)
#pragma unroll
        for (int nt = 0; nt < 4; ++nt)
          acc[mt][nt] = __builtin_amdgcn_mfma_f32_16x16x32_bf16(af[mt], bfr[nt], acc[mt][nt], 0, 0, 0);
    }
  }
  float nkv[4], lkv[4];
#pragma unroll
  for (int nt = 0; nt < 4; ++nt) {
    int gc = bn * 128 + n0 + nt * 16 + l15;
    nkv[nt] = nk[gc]; lkv[nt] = lk[gc];
  }
#pragma unroll
  for (int mt = 0; mt < 4; ++mt)
#pragma unroll
    for (int reg = 0; reg < 4; ++reg) {
      int gr = bm * 128 + m0 + mt * 16 + q4 * 4 + reg;
      float nqv = nq[gr], lqv = lq[gr];
#pragma unroll
      for (int nt = 0; nt < 4; ++nt) {
        int gc = bn * 128 + n0 + nt * 16 + l15;
        float d2 = nqv + nkv[nt] - 2.f * acc[mt][nt][reg];
        float Dv = sqrtf(fmaxf(d2, 0.f));
        Dout[gr * 2048 + gc] = Dv;
        float Pv = fabsf(lqv - lkv[nt]);
        DPo[gr * 2048 + gc] = (unsigned)f2bf(Dv) | ((unsigned)f2bf(Pv) << 16);
      }
    }
}

// ---------------- fused conv1+conv2+conv3+residual, row-pipelined ----------------
// Tile 62 out px x 32 out rows. 12 waves: w0-7 conv2, w8-9 conv1, w10-11 conv3+staging.
// LDS: dps 16-row ring [16][100] u32 (stride 100 breaks bank aliasing);
//      a1s [2][80 px][4 slot] int4 swizzled; a2s [2][68 px][4 slot] int4 swizzled.
// Staging + residual global loads are software-pipelined one barrier-interval
// ahead (round-4 lesson: same-iteration global->LDS put ~HBM latency on every
// barrier's critical path). All register arrays: compile-time indices ONLY.
__global__ __launch_bounds__(768, 3) void fused_conv(
    const unsigned* __restrict__ DPg, const float* __restrict__ Dmat,
    const unsigned short* __restrict__ W1g, const unsigned short* __restrict__ W2g,
    const unsigned short* __restrict__ W3g,
    const float* __restrict__ b1, const float* __restrict__ b2, const float* __restrict__ b3,
    float* __restrict__ Sout) {
  __shared__ int4 a1s[640];        // [2][80][4]
  __shared__ int4 a2s[544];        // [2][68][4]
  __shared__ unsigned dps[1600];   // [16][100]
  const int t = threadIdx.x;
  const int wv = t >> 6, l = t & 63, l15 = l & 15, q4 = l >> 4;
  const int x0 = blockIdx.x * 62, y0 = blockIdx.y * 32;

  int4 uni[25];     // conv2: A2[dy][s] ; conv3: shift regs [tt][3]
  int4 uni2[5];     // conv2: acc ring[5] ; conv1: A1p[j] ; conv3: A3[dx]
  float bias4[4];
  const int cls = (wv < 8) ? 0 : (wv < 10 ? 1 : 2);
  const int mb = (cls == 0) ? (wv >> 2) : (wv & 1);
  const int T2 = wv & 3;
  const int T3 = (wv - 10) * 2;

  // staging pipeline registers (cls 2 only)
  unsigned pvO = 0u;
  float d0O = 0.f, d1O = 0.f;
  const int spx = (wv == 10) ? l : (64 + l);
  const int sgx = x0 - 5 + spx;
  const bool scol = (spx < 96) && (sgx >= 0) && (sgx < 2048);

  if (cls == 0) {
    const int4* W2i = (const int4*)W2g;
#pragma unroll
    for (int d = 0; d < 5; ++d)
#pragma unroll
      for (int s = 0; s < 5; ++s)
        uni[d * 5 + s] = W2i[(d * 32 + mb * 16 + l15) * 20 + s * 4 + q4];
#pragma unroll
    for (int j = 0; j < 5; ++j) uni2[j] = make_int4(0, 0, 0, 0);
#pragma unroll
    for (int i = 0; i < 4; ++i) {
      int ch = mb * 16 + q4 * 4 + i;
      bias4[i] = (ch < 30) ? b2[ch] : 0.f;
    }
  } else if (cls == 1) {
    const int4* W1i = (const int4*)W1g;
#pragma unroll
    for (int j = 0; j < 3; ++j) uni2[j] = W1i[(j * 32 + mb * 16 + l15) * 4 + q4];
#pragma unroll
    for (int i = 0; i < 4; ++i) {
      int ch = mb * 16 + q4 * 4 + i;
      bias4[i] = (ch < 30) ? b1[ch] : 0.f;
    }
  } else {
    const int4* W3i = (const int4*)W3g;
#pragma unroll
    for (int dx = 0; dx < 3; ++dx)
      uni2[dx] = (l15 < 3) ? W3i[(l15 * 3 + dx) * 4 + q4] : make_int4(0, 0, 0, 0);
#pragma unroll
    for (int j = 0; j < 6; ++j) uni[j] = make_int4(0, 0, 0, 0);
    bias4[0] = b3[0];
    // prologue: preload DP row y0 (written to ring at end of first iteration)
    if (scol) pvO = DPg[y0 * 2048 + sgx];
  }
  // prefill DP rows y0-5 .. y0-1
  if (t < 480) {
    int row = y0 - 5 + t / 96, px = t % 96;
    int gx = x0 - 5 + px;
    unsigned v = 0u;
    if (row >= 0 && gx >= 0 && gx < 2048) v = DPg[row * 2048 + gx];
    dps[(row & 15) * 100 + px] = v;
  }
  // zero act2 pad px 64..67 (both slots)
  if (t >= 480 && t < 512) {
    int i = t - 480;
    int sl = i >> 4, rem = i & 15;
    a2s[(sl * 68 + 64 + (rem >> 2)) * 4 + (rem & 3)] = make_int4(0, 0, 0, 0);
  }
  __syncthreads();

  for (int r = y0 - 3; r <= y0 + 36; ++r) {
    if (cls == 0) {
      // ---- conv2: consume act1 row rc = r-1 (5-dy sliding accs) ----
      int rc = r - 1;
      if (rc >= y0 - 3 && rc <= y0 + 34) {
        int sl = rc & 1;
#pragma unroll
        for (int s = 0; s < 5; ++s) {
          int px = T2 * 16 + l15 + s;
          s8v B = as_s8(a1s[(sl * 80 + px) * 4 + (q4 ^ ((px >> 1) & 3))]);
#pragma unroll
          for (int d = 0; d < 5; ++d)
            uni2[4 - d] = as_i4(__builtin_amdgcn_mfma_f32_16x16x32_bf16(
                as_s8(uni[d * 5 + s]), B, as_f4(uni2[4 - d]), 0, 0, 0));
        }
      }
      // ---- emit act2 row r2c = r-3 (single bf16, swizzled) ----
      int r2c = r - 3;
      if (r2c >= y0 - 1 && r2c <= y0 + 32) {
        int px2 = T2 * 16 + l15;
        int gx2 = x0 - 1 + px2;
        bool ok = (r2c >= 0 && r2c < 2048 && gx2 >= 0 && gx2 < 2048);
        f4v a = as_f4(uni2[0]);
        ushort4 hv;
        hv.x = f2bf(ok ? fmaxf(a[0] + bias4[0], 0.f) : 0.f);
        hv.y = f2bf(ok ? fmaxf(a[1] + bias4[1], 0.f) : 0.f);
        hv.z = f2bf(ok ? fmaxf(a[2] + bias4[2], 0.f) : 0.f);
        hv.w = f2bf(ok ? fmaxf(a[3] + bias4[3], 0.f) : 0.f);
        int slot = (mb * 2 + (q4 >> 1)) ^ ((px2 >> 1) & 3);
        *(ushort4*)((unsigned short*)a2s + ((r2c & 1) * 68 + px2) * 32 + slot * 8 + (q4 & 1) * 4) = hv;
      }
#pragma unroll
      for (int j = 0; j < 4; ++j) uni2[j] = uni2[j + 1];
      uni2[4] = make_int4(0, 0, 0, 0);
    } else if (cls == 1) {
      // ---- conv1: produce act1 row r directly (dy-pair k-packed, 3 MFMA/px-tile) ----
      if (r >= y0 - 3 && r <= y0 + 34) {
        bool rowok = (r >= 0 && r < 2048);
#pragma unroll
        for (int T1 = 0; T1 < 5; ++T1) {
          int px = T1 * 16 + l15;
          f4v acc = {0.f, 0.f, 0.f, 0.f};
#pragma unroll
          for (int j = 0; j < 3; ++j) {
            int rlo = r - 2 + 2 * j;
            int rowsel = (j == 2) ? rlo : ((q4 < 2) ? rlo : (rlo + 1));
            int4 bi = *(const int4*)(dps + (rowsel & 15) * 100 + px + (q4 & 1) * 4);
            acc = __builtin_amdgcn_mfma_f32_16x16x32_bf16(as_s8(uni2[j]), as_s8(bi), acc, 0, 0, 0);
          }
          int gx = x0 - 3 + px;
          bool ok = rowok && gx >= 0 && gx < 2048;
          ushort4 sv;
          sv.x = f2bf(ok ? fmaxf(acc[0] + bias4[0], 0.f) : 0.f);
          sv.y = f2bf(ok ? fmaxf(acc[1] + bias4[1], 0.f) : 0.f);
          sv.z = f2bf(ok ? fmaxf(acc[2] + bias4[2], 0.f) : 0.f);
          sv.w = f2bf(ok ? fmaxf(acc[3] + bias4[3], 0.f) : 0.f);
          int slot = (mb * 2 + (q4 >> 1)) ^ ((px >> 1) & 3);
          *(ushort4*)((unsigned short*)a1s + ((r & 1) * 80 + px) * 32 + slot * 8 + (q4 & 1) * 4) = sv;
        }
      }
    } else {
      // ---- issue staging load for DP row r+4 (consumed NEXT iteration) ----
      int rsN = r + 4;
      unsigned pvN = 0u;
      if (scol && rsN <= y0 + 36 && rsN < 2048) pvN = DPg[rsN * 2048 + sgx];
      // ---- issue residual load for out row r-4 (consumed NEXT iteration) ----
      int yn = r - 4;
      float d0N = 0.f, d1N = 0.f;
      if (q4 == 0 && yn >= 0 && yn < 2048) {
        int gx0 = x0 + T3 * 16 + l15;
        if (gx0 < 2048) d0N = Dmat[yn * 2048 + gx0];
        if (gx0 + 16 < 2048) d1N = Dmat[yn * 2048 + gx0 + 16];
      }
      // ---- conv3: consume act2 row a = r-4 (m=dy trick: 3 MFMA per 16px tile) ----
      int a = r - 4;
      if (a >= y0 - 1 && a <= y0 + 32) {
        int sl = a & 1;
#pragma unroll
        for (int tt = 0; tt < 2; ++tt) {
          f4v acc3 = {0.f, 0.f, 0.f, 0.f};
#pragma unroll
          for (int dx = 0; dx < 3; ++dx) {
            int px2 = (T3 + tt) * 16 + l15 + dx;
            s8v B = as_s8(a2s[(sl * 68 + px2) * 4 + (q4 ^ ((px2 >> 1) & 3))]);
            acc3 = __builtin_amdgcn_mfma_f32_16x16x32_bf16(as_s8(uni2[dx]), B, acc3, 0, 0, 0);
          }
          uni[tt * 3 + 2] = as_i4(acc3);
        }
      }
      // ---- emit out row y = r-5 (uses residual loaded LAST iteration) ----
      int y = r - 5;
      if (y >= y0 && y <= y0 + 31) {
        {
          int ox = T3 * 16 + l15;
          int gx = x0 + ox;
          if (q4 == 0 && gx < 2048) {
            float val = as_f4(uni[0])[0] + as_f4(uni[1])[1] + as_f4(uni[2])[2]
                      + bias4[0] + d0O;
            Sout[y * 2048 + gx] = val;
          }
        }
        {
          int ox = (T3 + 1) * 16 + l15;
          int gx = x0 + ox;
          if (q4 == 0 && ox < 62 && gx < 2048) {
            float val = as_f4(uni[3])[0] + as_f4(uni[4])[1] + as_f4(uni[5])[2]
                      + bias4[0] + d1O;
            Sout[y * 2048 + gx] = val;
          }
        }
      }
      // shift conv3 accs (static moves)
#pragma unroll
      for (int tt = 0; tt < 2; ++tt) {
        uni[tt * 3 + 0] = uni[tt * 3 + 1];
        uni[tt * 3 + 1] = uni[tt * 3 + 2];
      }
      // ---- write staging row rs = r+3 from regs loaded LAST iteration ----
      int rs = r + 3;
      if (spx < 96 && rs <= y0 + 36) dps[(rs & 15) * 100 + spx] = pvO;
      pvO = pvN; d0O = d0N; d1O = d1N;
    }
    __syncthreads();
  }
}

// ---------------- row softmax (in-place on d_out) + dis accumulation ----------------
__global__ __launch_bounds__(256) void softmax_kernel(
    float* __restrict__ S, const float* __restrict__ Dmat, float* __restrict__ accum) {
  const int row = blockIdx.x, t = threadIdx.x;
  float* Srow = S + row * 2048;
  const float* Drow = Dmat + row * 2048;
  float sv[8], dv[8];
  float mx = -1e30f;
#pragma unroll
  for (int i = 0; i < 8; ++i) {
    sv[i] = -Srow[t + i * 256];
    dv[i] = Drow[t + i * 256];
    mx = fmaxf(mx, sv[i]);
  }
  __shared__ float red[4], redz[4], redw[4];
  for (int off = 32; off; off >>= 1) mx = fmaxf(mx, __shfl_xor(mx, off));
  const int wv = t >> 6, l = t & 63;
  if (l == 0) red[wv] = mx;
  __syncthreads();
  mx = fmaxf(fmaxf(red[0], red[1]), fmaxf(red[2], red[3]));
  float z = 0.f, w = 0.f, ev[8];
#pragma unroll
  for (int i = 0; i < 8; ++i) {
    ev[i] = __expf(sv[i] - mx);
    z += ev[i];
    w += ev[i] * dv[i];
  }
  for (int off = 32; off; off >>= 1) { z += __shfl_xor(z, off); w += __shfl_xor(w, off); }
  if (l == 0) { redz[wv] = z; redw[wv] = w; }
  __syncthreads();
  z = redz[0] + redz[1] + redz[2] + redz[3];
  w = redw[0] + redw[1] + redw[2] + redw[3];
  float inv = 1.f / z;
#pragma unroll
  for (int i = 0; i < 8; ++i) Srow[t + i * 256] = ev[i] * inv;
  if (t == 0) atomicAdd(accum, w * inv);
}

__global__ void finalize_kernel(const float* __restrict__ accum, float* __restrict__ out) {
  if (threadIdx.x == 0) out[0] = accum[0] * (1.f / 2048.f);
}

// ---------------- host ----------------
extern "C" void kernel_launch(void* const* d_in, const int* in_sizes, int n_in,
                              void* d_out, int out_size, void* d_ws, size_t ws_size,
                              hipStream_t stream) {
  const float* seq_q = (const float*)d_in[0];
  const float* seq_k = (const float*)d_in[1];
  const float* len_q = (const float*)d_in[2];
  const float* len_k = (const float*)d_in[3];
  const float* w1 = (const float*)d_in[4];
  const float* b1 = (const float*)d_in[5];
  const float* w2 = (const float*)d_in[6];
  const float* b2 = (const float*)d_in[7];
  const float* w3 = (const float*)d_in[8];
  const float* b3 = (const float*)d_in[9];

  char* ws = (char*)d_ws;
  unsigned short* Qb  = (unsigned short*)(ws);                         // 2 MiB
  unsigned short* Kb  = (unsigned short*)(ws + ((size_t)2 << 20));     // 2 MiB
  float* nq           = (float*)(ws + ((size_t)4 << 20));              // 8 KiB
  float* nk           = (float*)(ws + ((size_t)4 << 20) + 16384);
  unsigned short* W1  = (unsigned short*)(ws + ((size_t)4 << 20) + 32768);   // 6 KiB (packed)
  unsigned short* W2  = (unsigned short*)(ws + ((size_t)4 << 20) + 65536);   // 50 KiB
  unsigned short* W3  = (unsigned short*)(ws + ((size_t)4 << 20) + 131072);  // 576 B
  float* accum        = (float*)(ws + ((size_t)4 << 20) + 163840);
  float* Dmat         = (float*)(ws + ((size_t)5 << 20));              // 16 MiB fp32
  unsigned* DPo       = (unsigned*)(ws + ((size_t)22 << 20));          // 16 MiB packed (D,P)
  float* out = (float*)d_out;

  const int prep_total = 2 * 2048 * 512 + 3072 + 25600 + 288 + 1;
  prep_kernel<<<(prep_total + 255) / 256, 256, 0, stream>>>(
      seq_q, seq_k, w1, w2, w3, Qb, Kb, W1, W2, W3, accum);
  norms_kernel<<<1024, 256, 0, stream>>>(seq_q, seq_k, nq, nk);
  dgemm_kernel<<<dim3(16, 16), 256, 0, stream>>>(Qb, Kb, nq, nk, len_q, len_k, Dmat, DPo);
  fused_conv<<<dim3(34, 64), 768, 0, stream>>>(
      DPo, Dmat, W1, W2, W3, b1, b2, b3, out);
  softmax_kernel<<<2048, 256, 0, stream>>>(out, Dmat, accum);
  finalize_kernel<<<1, 64, 0, stream>>>(accum, out + 4194304);
}